// Round 1
// baseline (6294.365 us; speedup 1.0000x reference)
//
#include <hip/hip_runtime.h>
#include <math.h>

#define HEADS 4
#define HID 64
#define D1 256
#define NGR 1024
#define NEG 0.2f

static inline int cdiv(int a, int b) { return (a + b - 1) / b; }

__device__ inline void atomicMaxF(float* a, float v) {
    if (v >= 0.f) atomicMax((int*)a, __float_as_int(v));
    else atomicMin((unsigned int*)a, __float_as_uint(v));
}

__global__ void k_fill(float* __restrict__ p, float v, int n) {
    int i = blockIdx.x * blockDim.x + threadIdx.x;
    if (i < n) p[i] = v;
}

// xw = x @ W1, x:[N,6], W1:[6,256]
__global__ void k_xw1(const float* __restrict__ x, const float* __restrict__ W,
                      float* __restrict__ xw, int N) {
    int i = blockIdx.x * blockDim.x + threadIdx.x;
    if (i >= N * D1) return;
    int n = i >> 8, c = i & 255;
    const float* xr = x + n * 6;
    float acc = 0.f;
#pragma unroll
    for (int k = 0; k < 6; ++k) acc += xr[k] * W[k * D1 + c];
    xw[i] = acc;
}

// alpha_s/alpha_d per (node, head)
__global__ void k_alpha(const float* __restrict__ xw, const float* __restrict__ av,
                        const float* __restrict__ dv, float* __restrict__ as_,
                        float* __restrict__ ad_, int N) {
    int i = blockIdx.x * blockDim.x + threadIdx.x;
    if (i >= N * HEADS) return;
    int n = i >> 2, h = i & 3;
    const float* row = xw + (size_t)n * D1 + h * HID;
    const float* a = av + h * HID;
    const float* d = dv + h * HID;
    float s = 0.f, t = 0.f;
#pragma unroll 8
    for (int j = 0; j < HID; ++j) { float v = row[j]; s += v * a[j]; t += v * d[j]; }
    as_[i] = s; ad_[i] = t;
}

// pass A: e = lrelu(as[src]+ad[dst]); atomicMax m[dst]
__global__ void k_edgeA(const int* __restrict__ ei, int E, int ET,
                        const float* __restrict__ as_, const float* __restrict__ ad_,
                        float* __restrict__ ebuf, float* __restrict__ m) {
    int i = blockIdx.x * blockDim.x + threadIdx.x;
    if (i >= ET * HEADS) return;
    int e = i >> 2, h = i & 3;
    int s, d;
    if (e < E) { s = ei[e]; d = ei[E + e]; } else { s = d = e - E; }
    float v = as_[s * HEADS + h] + ad_[d * HEADS + h];
    v = v > 0.f ? v : NEG * v;
    ebuf[i] = v;
    atomicMaxF(&m[d * HEADS + h], v);
}

// pass B: ex = exp(e - m[dst]); atomicAdd den[dst]
__global__ void k_edgeB(const int* __restrict__ ei, int E, int ET,
                        const float* __restrict__ m, float* __restrict__ ebuf,
                        float* __restrict__ den) {
    int i = blockIdx.x * blockDim.x + threadIdx.x;
    if (i >= ET * HEADS) return;
    int e = i >> 2, h = i & 3;
    int d = (e < E) ? ei[E + e] : e - E;
    float ex = expf(ebuf[i] - m[d * HEADS + h]);
    ebuf[i] = ex;
    atomicAdd(&den[d * HEADS + h], ex);
}

// pass C: one wave per edge; out[dst] += alpha * xw[src]
__global__ void k_edgeC(const int* __restrict__ ei, int E, int ET,
                        const float* __restrict__ ebuf, const float* __restrict__ den,
                        const float* __restrict__ xw, float* __restrict__ out) {
    int e = blockIdx.x * 4 + (threadIdx.x >> 6);
    if (e >= ET) return;
    int t = threadIdx.x & 63;
    int s, d;
    if (e < E) { s = ei[e]; d = ei[E + e]; } else { s = d = e - E; }
    int h = t >> 4;
    float a = ebuf[e * HEADS + h] / (den[d * HEADS + h] + 1e-16f);
    float4 v = ((const float4*)(xw + (size_t)s * D1))[t];
    float* o = out + (size_t)d * D1 + t * 4;
    atomicAdd(o + 0, a * v.x);
    atomicAdd(o + 1, a * v.y);
    atomicAdd(o + 2, a * v.z);
    atomicAdd(o + 3, a * v.w);
}

__global__ void k_elu_bias(float* __restrict__ out, const float* __restrict__ b, int N) {
    int i = blockIdx.x * blockDim.x + threadIdx.x;
    if (i >= N * D1) return;
    float v = out[i] + b[i & 255];
    out[i] = v > 0.f ? v : (expf(v) - 1.f);
}

// xw = h @ W2, h:[N,256], W2:[256,256]; 4 nodes per block
#define NPB 4
__global__ void k_xw2(const float* __restrict__ hin, const float* __restrict__ W,
                      float* __restrict__ xw, int N) {
    __shared__ float sh[NPB][D1];
    int n0 = blockIdx.x * NPB;
    int c = threadIdx.x;
#pragma unroll
    for (int mi = 0; mi < NPB; ++mi) {
        int n = n0 + mi;
        sh[mi][c] = (n < N) ? hin[(size_t)n * D1 + c] : 0.f;
    }
    __syncthreads();
    float acc0 = 0.f, acc1 = 0.f, acc2 = 0.f, acc3 = 0.f;
    for (int k = 0; k < D1; k += 4) {
        float4 h0 = *(const float4*)&sh[0][k];
        float4 h1 = *(const float4*)&sh[1][k];
        float4 h2 = *(const float4*)&sh[2][k];
        float4 h3 = *(const float4*)&sh[3][k];
        float w0 = W[(k + 0) * D1 + c];
        float w1 = W[(k + 1) * D1 + c];
        float w2 = W[(k + 2) * D1 + c];
        float w3 = W[(k + 3) * D1 + c];
        acc0 += h0.x * w0 + h0.y * w1 + h0.z * w2 + h0.w * w3;
        acc1 += h1.x * w0 + h1.y * w1 + h1.z * w2 + h1.w * w3;
        acc2 += h2.x * w0 + h2.y * w1 + h2.z * w2 + h2.w * w3;
        acc3 += h3.x * w0 + h3.y * w1 + h3.z * w2 + h3.w * w3;
    }
    if (n0 + 0 < N) xw[(size_t)(n0 + 0) * D1 + c] = acc0;
    if (n0 + 1 < N) xw[(size_t)(n0 + 1) * D1 + c] = acc1;
    if (n0 + 2 < N) xw[(size_t)(n0 + 2) * D1 + c] = acc2;
    if (n0 + 3 < N) xw[(size_t)(n0 + 3) * D1 + c] = acc3;
}

// mean-pool accumulation
__global__ void k_pool(const float* __restrict__ h, const int* __restrict__ batch,
                       float* __restrict__ pooled, float* __restrict__ cnt, int N) {
    int i = blockIdx.x * blockDim.x + threadIdx.x;
    if (i >= N * D1) return;
    int n = i >> 8, c = i & 255;
    int b = batch[n];
    atomicAdd(&pooled[(size_t)b * D1 + c], h[i]);
    if (c == 0) atomicAdd(&cnt[b], 1.0f);
}

__device__ inline float knotf(int j) { return (j - 3) * 0.4f - 1.0f; }

__device__ inline void bspl8(float x, float* out) {
    float t[12];
#pragma unroll
    for (int j = 0; j < 12; ++j) t[j] = knotf(j);
    float bb[11];
#pragma unroll
    for (int j = 0; j < 11; ++j) bb[j] = (x >= t[j] && x < t[j + 1]) ? 1.f : 0.f;
#pragma unroll
    for (int k = 1; k <= 3; ++k) {
#pragma unroll
        for (int j = 0; j + k < 11; ++j) {
            float dl = t[j + k] - t[j];
            float dr = t[j + k + 1] - t[j + 1];
            bb[j] = (x - t[j]) / dl * bb[j] + (t[j + k + 1] - x) / dr * bb[j + 1];
        }
    }
#pragma unroll
    for (int p = 0; p < 8; ++p) out[p] = bb[p];
}

__device__ inline float siluf(float x) { return x / (1.f + expf(-x)); }

// fused KAN: one block per graph
__global__ void k_kan(const float* __restrict__ pooled, const float* __restrict__ cnt,
                      const float* __restrict__ bw1, const float* __restrict__ sw1,
                      const float* __restrict__ sc1, const float* __restrict__ bw2,
                      const float* __restrict__ sw2, const float* __restrict__ sc2,
                      float* __restrict__ out) {
    __shared__ float sB[D1][8];
    __shared__ float sS[D1];
    __shared__ float sR[D1];
    __shared__ float sZ[32];
    int g = blockIdx.x;
    int i = threadIdx.x;
    float cg = fmaxf(cnt[g], 1.0f);
    float xi = pooled[(size_t)g * D1 + i] / cg;
    float b[8];
    bspl8(xi, b);
#pragma unroll
    for (int p = 0; p < 8; ++p) sB[i][p] = b[p];
    sS[i] = siluf(xi);
    __syncthreads();
    for (int o = 0; o < 32; ++o) {
        float sc = sc1[o * D1 + i];
        float part = sS[i] * bw1[o * D1 + i];
        const float* sw = sw1 + ((size_t)o * D1 + i) * 8;
#pragma unroll
        for (int p = 0; p < 8; ++p) part += sB[i][p] * sw[p] * sc;
        sR[i] = part;
        __syncthreads();
        if (i < 128) sR[i] += sR[i + 128];
        __syncthreads();
        if (i < 64) {
            float v = sR[i] + sR[i + 64];
#pragma unroll
            for (int off = 32; off >= 1; off >>= 1) v += __shfl_down(v, off);
            if (i == 0) sZ[o] = v;
        }
        __syncthreads();
    }
    if (i < 64) {
        float part = 0.f;
        if (i < 32) {
            float z = sZ[i];
            float b2[8];
            bspl8(z, b2);
            part = siluf(z) * bw2[i];
            float sc = sc2[i];
#pragma unroll
            for (int p = 0; p < 8; ++p) part += b2[p] * sw2[i * 8 + p] * sc;
        }
#pragma unroll
        for (int off = 32; off >= 1; off >>= 1) part += __shfl_down(part, off);
        if (i == 0) out[g] = part;
    }
}

extern "C" void kernel_launch(void* const* d_in, const int* in_sizes, int n_in,
                              void* d_out, int out_size, void* d_ws, size_t ws_size,
                              hipStream_t stream) {
    const float* x      = (const float*)d_in[0];
    const int*   ei     = (const int*)d_in[1];
    const int*   batch  = (const int*)d_in[2];
    const float* W1     = (const float*)d_in[3];
    const float* asrc1  = (const float*)d_in[4];
    const float* adst1  = (const float*)d_in[5];
    const float* b1     = (const float*)d_in[6];
    const float* W2     = (const float*)d_in[7];
    const float* asrc2  = (const float*)d_in[8];
    const float* adst2  = (const float*)d_in[9];
    const float* b2     = (const float*)d_in[10];
    const float* bw1    = (const float*)d_in[11];
    const float* sw1    = (const float*)d_in[12];
    const float* sc1    = (const float*)d_in[13];
    const float* bw2    = (const float*)d_in[14];
    const float* sw2    = (const float*)d_in[15];
    const float* sc2    = (const float*)d_in[16];
    float* outp = (float*)d_out;

    const int N  = in_sizes[0] / 6;
    const int E  = in_sizes[1] / 2;
    const int ET = E + N;

    float* ws     = (float*)d_ws;
    float* xw     = ws;                    // N*256
    float* hbuf   = xw + (size_t)N * D1;   // N*256
    float* ebuf   = hbuf + (size_t)N * D1; // ET*4
    float* as_    = ebuf + (size_t)ET * HEADS;
    float* ad_    = as_ + (size_t)N * HEADS;
    float* mbuf   = ad_ + (size_t)N * HEADS;
    float* den    = mbuf + (size_t)N * HEADS;
    float* pooled = den + (size_t)N * HEADS;   // NGR*256
    float* cnt    = pooled + (size_t)NGR * D1; // NGR

    const int TB = 256;
    int gNC = cdiv(N * D1, TB);
    int gNH = cdiv(N * HEADS, TB);
    int gEH = cdiv(ET * HEADS, TB);
    int gEC = cdiv(ET, 4);

    // ---------------- layer 1 ----------------
    hipMemsetAsync(hbuf, 0, (size_t)N * D1 * sizeof(float), stream);
    k_xw1<<<gNC, TB, 0, stream>>>(x, W1, xw, N);
    k_alpha<<<gNH, TB, 0, stream>>>(xw, asrc1, adst1, as_, ad_, N);
    k_fill<<<gNH, TB, 0, stream>>>(mbuf, -INFINITY, N * HEADS);
    hipMemsetAsync(den, 0, (size_t)N * HEADS * sizeof(float), stream);
    k_edgeA<<<gEH, TB, 0, stream>>>(ei, E, ET, as_, ad_, ebuf, mbuf);
    k_edgeB<<<gEH, TB, 0, stream>>>(ei, E, ET, mbuf, ebuf, den);
    k_edgeC<<<gEC, TB, 0, stream>>>(ei, E, ET, ebuf, den, xw, hbuf);
    k_elu_bias<<<gNC, TB, 0, stream>>>(hbuf, b1, N);

    // ---------------- layer 2 ----------------
    k_xw2<<<cdiv(N, NPB), TB, 0, stream>>>(hbuf, W2, xw, N);
    k_alpha<<<gNH, TB, 0, stream>>>(xw, asrc2, adst2, as_, ad_, N);
    k_fill<<<gNH, TB, 0, stream>>>(mbuf, -INFINITY, N * HEADS);
    hipMemsetAsync(den, 0, (size_t)N * HEADS * sizeof(float), stream);
    hipMemsetAsync(hbuf, 0, (size_t)N * D1 * sizeof(float), stream);
    k_edgeA<<<gEH, TB, 0, stream>>>(ei, E, ET, as_, ad_, ebuf, mbuf);
    k_edgeB<<<gEH, TB, 0, stream>>>(ei, E, ET, mbuf, ebuf, den);
    k_edgeC<<<gEC, TB, 0, stream>>>(ei, E, ET, ebuf, den, xw, hbuf);
    k_elu_bias<<<gNC, TB, 0, stream>>>(hbuf, b2, N);

    // ---------------- pool + KAN ----------------
    hipMemsetAsync(pooled, 0, (size_t)NGR * D1 * sizeof(float), stream);
    hipMemsetAsync(cnt, 0, (size_t)NGR * sizeof(float), stream);
    k_pool<<<gNC, TB, 0, stream>>>(hbuf, batch, pooled, cnt, N);
    k_kan<<<NGR, TB, 0, stream>>>(pooled, cnt, bw1, sw1, sc1, bw2, sw2, sc2, outp);
}

// Round 2
// 798.333 us; speedup vs baseline: 7.8844x; 7.8844x over previous
//
#include <hip/hip_runtime.h>
#include <math.h>

#define HEADS 4
#define HID 64
#define D1 256
#define NGR 1024
#define NEG 0.2f

static inline int cdiv(int a, int b) { return (a + b - 1) / b; }

// ---------------- CSR build ----------------

__global__ void k_deg(const int* __restrict__ ei, int E, int ET, int* __restrict__ deg) {
    int e = blockIdx.x * blockDim.x + threadIdx.x;
    if (e >= ET) return;
    int d = (e < E) ? ei[E + e] : e - E;
    atomicAdd(&deg[d], 1);
}

// single-block exclusive scan of deg[0..N) -> rowp[0..N]
__global__ void k_scan(const int* __restrict__ deg, int* __restrict__ rowp, int N) {
    __shared__ int ssum[1024];
    int t = threadIdx.x;
    int chunk = (N + 1023) / 1024;
    int lo = t * chunk, hi = min(lo + chunk, N);
    int s = 0;
    for (int i = lo; i < hi; ++i) s += deg[i];
    ssum[t] = s;
    __syncthreads();
    for (int off = 1; off < 1024; off <<= 1) {
        int v = 0;
        if (t >= off) v = ssum[t - off];
        __syncthreads();
        ssum[t] += v;
        __syncthreads();
    }
    int run = ssum[t] - s;  // exclusive prefix of this chunk
    for (int i = lo; i < hi; ++i) { rowp[i] = run; run += deg[i]; }
    if (t == 1023) rowp[N] = ssum[1023];
}

__global__ void k_scatter(const int* __restrict__ ei, int E, int ET,
                          const int* __restrict__ rowp, int* __restrict__ fill,
                          int* __restrict__ csrc) {
    int e = blockIdx.x * blockDim.x + threadIdx.x;
    if (e >= ET) return;
    int s, d;
    if (e < E) { s = ei[e]; d = ei[E + e]; } else { s = d = e - E; }
    int pos = rowp[d] + atomicAdd(&fill[d], 1);
    csrc[pos] = s;
}

// ---------------- dense precompute ----------------

// xw = x @ W1, x:[N,6], W1:[6,256]
__global__ void k_xw1(const float* __restrict__ x, const float* __restrict__ W,
                      float* __restrict__ xw, int N) {
    int i = blockIdx.x * blockDim.x + threadIdx.x;
    if (i >= N * D1) return;
    int n = i >> 8, c = i & 255;
    const float* xr = x + n * 6;
    float acc = 0.f;
#pragma unroll
    for (int k = 0; k < 6; ++k) acc += xr[k] * W[k * D1 + c];
    xw[i] = acc;
}

// alpha_s/alpha_d per (node, head)
__global__ void k_alpha(const float* __restrict__ xw, const float* __restrict__ av,
                        const float* __restrict__ dv, float* __restrict__ as_,
                        float* __restrict__ ad_, int N) {
    int i = blockIdx.x * blockDim.x + threadIdx.x;
    if (i >= N * HEADS) return;
    int n = i >> 2, h = i & 3;
    const float* row = xw + (size_t)n * D1 + h * HID;
    const float* a = av + h * HID;
    const float* d = dv + h * HID;
    float s = 0.f, t = 0.f;
#pragma unroll 8
    for (int j = 0; j < HID; ++j) { float v = row[j]; s += v * a[j]; t += v * d[j]; }
    as_[i] = s; ad_[i] = t;
}

// ---------------- fused GAT aggregate: one wave per dst ----------------
// out[d] = elu( (sum_e exp(lrelu(as[s]+ad[d]) - m) * xw[s]) / den + bias )
__global__ void k_aggr(const int* __restrict__ rowp, const int* __restrict__ csrc,
                       const float* __restrict__ as_, const float* __restrict__ ad_,
                       const float* __restrict__ xw, const float* __restrict__ bias,
                       float* __restrict__ out, int N) {
    int d = blockIdx.x * 4 + (threadIdx.x >> 6);
    if (d >= N) return;
    int t = threadIdx.x & 63;
    int h = t >> 4;
    int lo = rowp[d], hi = rowp[d + 1];
    float adh = ad_[d * HEADS + h];

    // phase 1: per-head max. Lanes (t&15) of head h cover edges strided by 16.
    float mx = -INFINITY;
    for (int k = lo + (t & 15); k < hi; k += 16) {
        int s = csrc[k];
        float v = as_[s * HEADS + h] + adh;
        v = v > 0.f ? v : NEG * v;
        mx = fmaxf(mx, v);
    }
#pragma unroll
    for (int off = 1; off < 16; off <<= 1) mx = fmaxf(mx, __shfl_xor(mx, off));

    // phase 2: accumulate exp-weighted messages (unnormalized) + denominator
    float4 acc = {0.f, 0.f, 0.f, 0.f};
    float den = 0.f;
    int k = lo;
    for (; k + 1 < hi; k += 2) {
        int s0 = csrc[k], s1 = csrc[k + 1];
        float v0 = as_[s0 * HEADS + h] + adh;
        float v1 = as_[s1 * HEADS + h] + adh;
        v0 = v0 > 0.f ? v0 : NEG * v0;
        v1 = v1 > 0.f ? v1 : NEG * v1;
        float e0 = __expf(v0 - mx);
        float e1 = __expf(v1 - mx);
        float4 x0 = ((const float4*)(xw + (size_t)s0 * D1))[t];
        float4 x1 = ((const float4*)(xw + (size_t)s1 * D1))[t];
        den += e0 + e1;
        acc.x += e0 * x0.x + e1 * x1.x;
        acc.y += e0 * x0.y + e1 * x1.y;
        acc.z += e0 * x0.z + e1 * x1.z;
        acc.w += e0 * x0.w + e1 * x1.w;
    }
    if (k < hi) {
        int s0 = csrc[k];
        float v0 = as_[s0 * HEADS + h] + adh;
        v0 = v0 > 0.f ? v0 : NEG * v0;
        float e0 = __expf(v0 - mx);
        float4 x0 = ((const float4*)(xw + (size_t)s0 * D1))[t];
        den += e0;
        acc.x += e0 * x0.x; acc.y += e0 * x0.y; acc.z += e0 * x0.z; acc.w += e0 * x0.w;
    }
    float inv = 1.f / (den + 1e-16f);
    float4 bv = ((const float4*)bias)[t];
    float4 o;
    o.x = acc.x * inv + bv.x;
    o.y = acc.y * inv + bv.y;
    o.z = acc.z * inv + bv.z;
    o.w = acc.w * inv + bv.w;
    o.x = o.x > 0.f ? o.x : (__expf(o.x) - 1.f);
    o.y = o.y > 0.f ? o.y : (__expf(o.y) - 1.f);
    o.z = o.z > 0.f ? o.z : (__expf(o.z) - 1.f);
    o.w = o.w > 0.f ? o.w : (__expf(o.w) - 1.f);
    ((float4*)(out + (size_t)d * D1))[t] = o;
}

// ---------------- xw = h @ W2, h:[N,256], W2:[256,256]; 4 nodes/block ----------------
#define NPB 4
__global__ void k_xw2(const float* __restrict__ hin, const float* __restrict__ W,
                      float* __restrict__ xw, int N) {
    __shared__ float sh[NPB][D1];
    int n0 = blockIdx.x * NPB;
    int c = threadIdx.x;
#pragma unroll
    for (int mi = 0; mi < NPB; ++mi) {
        int n = n0 + mi;
        sh[mi][c] = (n < N) ? hin[(size_t)n * D1 + c] : 0.f;
    }
    __syncthreads();
    float acc0 = 0.f, acc1 = 0.f, acc2 = 0.f, acc3 = 0.f;
    for (int k = 0; k < D1; k += 4) {
        float4 h0 = *(const float4*)&sh[0][k];
        float4 h1 = *(const float4*)&sh[1][k];
        float4 h2 = *(const float4*)&sh[2][k];
        float4 h3 = *(const float4*)&sh[3][k];
        float w0 = W[(k + 0) * D1 + c];
        float w1 = W[(k + 1) * D1 + c];
        float w2 = W[(k + 2) * D1 + c];
        float w3 = W[(k + 3) * D1 + c];
        acc0 += h0.x * w0 + h0.y * w1 + h0.z * w2 + h0.w * w3;
        acc1 += h1.x * w0 + h1.y * w1 + h1.z * w2 + h1.w * w3;
        acc2 += h2.x * w0 + h2.y * w1 + h2.z * w2 + h2.w * w3;
        acc3 += h3.x * w0 + h3.y * w1 + h3.z * w2 + h3.w * w3;
    }
    if (n0 + 0 < N) xw[(size_t)(n0 + 0) * D1 + c] = acc0;
    if (n0 + 1 < N) xw[(size_t)(n0 + 1) * D1 + c] = acc1;
    if (n0 + 2 < N) xw[(size_t)(n0 + 2) * D1 + c] = acc2;
    if (n0 + 3 < N) xw[(size_t)(n0 + 3) * D1 + c] = acc3;
}

// ---------------- mean-pool accumulation ----------------
__global__ void k_pool(const float* __restrict__ h, const int* __restrict__ batch,
                       float* __restrict__ pooled, float* __restrict__ cnt, int N) {
    int i = blockIdx.x * blockDim.x + threadIdx.x;
    if (i >= N * D1) return;
    int n = i >> 8, c = i & 255;
    int b = batch[n];
    atomicAdd(&pooled[(size_t)b * D1 + c], h[i]);
    if (c == 0) atomicAdd(&cnt[b], 1.0f);
}

// ---------------- KAN ----------------

__device__ inline float knotf(int j) { return (j - 3) * 0.4f - 1.0f; }

__device__ inline void bspl8(float x, float* out) {
    float t[12];
#pragma unroll
    for (int j = 0; j < 12; ++j) t[j] = knotf(j);
    float bb[11];
#pragma unroll
    for (int j = 0; j < 11; ++j) bb[j] = (x >= t[j] && x < t[j + 1]) ? 1.f : 0.f;
#pragma unroll
    for (int k = 1; k <= 3; ++k) {
#pragma unroll
        for (int j = 0; j + k < 11; ++j) {
            float dl = t[j + k] - t[j];
            float dr = t[j + k + 1] - t[j + 1];
            bb[j] = (x - t[j]) / dl * bb[j] + (t[j + k + 1] - x) / dr * bb[j + 1];
        }
    }
#pragma unroll
    for (int p = 0; p < 8; ++p) out[p] = bb[p];
}

__device__ inline float siluf(float x) { return x / (1.f + __expf(-x)); }

// fused KAN: one block per graph
__global__ void k_kan(const float* __restrict__ pooled, const float* __restrict__ cnt,
                      const float* __restrict__ bw1, const float* __restrict__ sw1,
                      const float* __restrict__ sc1, const float* __restrict__ bw2,
                      const float* __restrict__ sw2, const float* __restrict__ sc2,
                      float* __restrict__ out) {
    __shared__ float sB[D1][8];
    __shared__ float sS[D1];
    __shared__ float sR[D1];
    __shared__ float sZ[32];
    int g = blockIdx.x;
    int i = threadIdx.x;
    float cg = fmaxf(cnt[g], 1.0f);
    float xi = pooled[(size_t)g * D1 + i] / cg;
    float b[8];
    bspl8(xi, b);
#pragma unroll
    for (int p = 0; p < 8; ++p) sB[i][p] = b[p];
    sS[i] = siluf(xi);
    __syncthreads();
    for (int o = 0; o < 32; ++o) {
        float sc = sc1[o * D1 + i];
        float part = sS[i] * bw1[o * D1 + i];
        const float* sw = sw1 + ((size_t)o * D1 + i) * 8;
#pragma unroll
        for (int p = 0; p < 8; ++p) part += sB[i][p] * sw[p] * sc;
        sR[i] = part;
        __syncthreads();
        if (i < 128) sR[i] += sR[i + 128];
        __syncthreads();
        if (i < 64) {
            float v = sR[i] + sR[i + 64];
#pragma unroll
            for (int off = 32; off >= 1; off >>= 1) v += __shfl_down(v, off);
            if (i == 0) sZ[o] = v;
        }
        __syncthreads();
    }
    if (i < 64) {
        float part = 0.f;
        if (i < 32) {
            float z = sZ[i];
            float b2[8];
            bspl8(z, b2);
            part = siluf(z) * bw2[i];
            float sc = sc2[i];
#pragma unroll
            for (int p = 0; p < 8; ++p) part += b2[p] * sw2[i * 8 + p] * sc;
        }
#pragma unroll
        for (int off = 32; off >= 1; off >>= 1) part += __shfl_down(part, off);
        if (i == 0) out[g] = part;
    }
}

extern "C" void kernel_launch(void* const* d_in, const int* in_sizes, int n_in,
                              void* d_out, int out_size, void* d_ws, size_t ws_size,
                              hipStream_t stream) {
    const float* x      = (const float*)d_in[0];
    const int*   ei     = (const int*)d_in[1];
    const int*   batch  = (const int*)d_in[2];
    const float* W1     = (const float*)d_in[3];
    const float* asrc1  = (const float*)d_in[4];
    const float* adst1  = (const float*)d_in[5];
    const float* b1     = (const float*)d_in[6];
    const float* W2     = (const float*)d_in[7];
    const float* asrc2  = (const float*)d_in[8];
    const float* adst2  = (const float*)d_in[9];
    const float* b2     = (const float*)d_in[10];
    const float* bw1    = (const float*)d_in[11];
    const float* sw1    = (const float*)d_in[12];
    const float* sc1    = (const float*)d_in[13];
    const float* bw2    = (const float*)d_in[14];
    const float* sw2    = (const float*)d_in[15];
    const float* sc2    = (const float*)d_in[16];
    float* outp = (float*)d_out;

    const int N  = in_sizes[0] / 6;
    const int E  = in_sizes[1] / 2;
    const int ET = E + N;

    float* ws     = (float*)d_ws;
    float* xw     = ws;                        // N*256
    float* hbuf   = xw + (size_t)N * D1;       // N*256
    float* as_    = hbuf + (size_t)N * D1;     // N*4
    float* ad_    = as_ + (size_t)N * HEADS;   // N*4
    float* pooled = ad_ + (size_t)N * HEADS;   // NGR*256
    float* cnt    = pooled + (size_t)NGR * D1; // NGR
    int*   deg    = (int*)(cnt + NGR);         // N
    int*   fill   = deg + N;                   // N
    int*   rowp   = fill + N;                  // N+1
    int*   csrc   = rowp + N + 1;              // ET

    const int TB = 256;
    int gNC = cdiv(N * D1, TB);
    int gNH = cdiv(N * HEADS, TB);
    int gET = cdiv(ET, TB);
    int gAG = cdiv(N, 4);

    // ---------------- CSR build (shared by both layers) ----------------
    hipMemsetAsync(deg, 0, (size_t)N * sizeof(int), stream);
    hipMemsetAsync(fill, 0, (size_t)N * sizeof(int), stream);
    k_deg<<<gET, TB, 0, stream>>>(ei, E, ET, deg);
    k_scan<<<1, 1024, 0, stream>>>(deg, rowp, N);
    k_scatter<<<gET, TB, 0, stream>>>(ei, E, ET, rowp, fill, csrc);

    // ---------------- layer 1 ----------------
    k_xw1<<<gNC, TB, 0, stream>>>(x, W1, xw, N);
    k_alpha<<<gNH, TB, 0, stream>>>(xw, asrc1, adst1, as_, ad_, N);
    k_aggr<<<gAG, TB, 0, stream>>>(rowp, csrc, as_, ad_, xw, b1, hbuf, N);

    // ---------------- layer 2 ----------------
    k_xw2<<<cdiv(N, NPB), TB, 0, stream>>>(hbuf, W2, xw, N);
    k_alpha<<<gNH, TB, 0, stream>>>(xw, asrc2, adst2, as_, ad_, N);
    k_aggr<<<gAG, TB, 0, stream>>>(rowp, csrc, as_, ad_, xw, b2, hbuf, N);

    // ---------------- pool + KAN ----------------
    hipMemsetAsync(pooled, 0, (size_t)NGR * D1 * sizeof(float), stream);
    hipMemsetAsync(cnt, 0, (size_t)NGR * sizeof(float), stream);
    k_pool<<<gNC, TB, 0, stream>>>(hbuf, batch, pooled, cnt, N);
    k_kan<<<NGR, TB, 0, stream>>>(pooled, cnt, bw1, sw1, sc1, bw2, sw2, sc2, outp);
}

// Round 3
// 504.153 us; speedup vs baseline: 12.4850x; 1.5835x over previous
//
#include <hip/hip_runtime.h>
#include <math.h>

#define HEADS 4
#define HID 64
#define D1 256
#define NGR 1024
#define NEG 0.2f

typedef __attribute__((ext_vector_type(8))) short bf16x8;
typedef __attribute__((ext_vector_type(4))) float f32x4;

static inline int cdiv(int a, int b) { return (a + b - 1) / b; }

__device__ inline unsigned short f2b(float f) {
    union { float f; unsigned u; } v; v.f = f;
    unsigned r = v.u + 0x7FFFu + ((v.u >> 16) & 1u);
    return (unsigned short)(r >> 16);
}
__device__ inline float b2f(unsigned short u) {
    union { unsigned u; float f; } v; v.u = ((unsigned)u) << 16;
    return v.f;
}

// ---------------- CSR build ----------------

__global__ void k_deg(const int* __restrict__ ei, int E, int ET, int* __restrict__ deg) {
    int e = blockIdx.x * blockDim.x + threadIdx.x;
    if (e >= ET) return;
    int d = (e < E) ? ei[E + e] : e - E;
    atomicAdd(&deg[d], 1);
}

__global__ void k_scan(const int* __restrict__ deg, int* __restrict__ rowp, int N) {
    __shared__ int ssum[1024];
    int t = threadIdx.x;
    int chunk = (N + 1023) / 1024;
    int lo = t * chunk, hi = min(lo + chunk, N);
    int s = 0;
    for (int i = lo; i < hi; ++i) s += deg[i];
    ssum[t] = s;
    __syncthreads();
    for (int off = 1; off < 1024; off <<= 1) {
        int v = 0;
        if (t >= off) v = ssum[t - off];
        __syncthreads();
        ssum[t] += v;
        __syncthreads();
    }
    int run = ssum[t] - s;
    for (int i = lo; i < hi; ++i) { rowp[i] = run; run += deg[i]; }
    if (t == 1023) rowp[N] = ssum[1023];
}

__global__ void k_scatter(const int* __restrict__ ei, int E, int ET,
                          const int* __restrict__ rowp, int* __restrict__ fill,
                          int* __restrict__ csrc) {
    int e = blockIdx.x * blockDim.x + threadIdx.x;
    if (e >= ET) return;
    int s, d;
    if (e < E) { s = ei[e]; d = ei[E + e]; } else { s = d = e - E; }
    int pos = rowp[d] + atomicAdd(&fill[d], 1);
    csrc[pos] = s;
}

// ---------------- dense precompute ----------------

// xb = bf16(x @ W1), x:[N,6], W1:[6,256]
__global__ void k_xw1(const float* __restrict__ x, const float* __restrict__ W,
                      unsigned short* __restrict__ xb, int N) {
    int i = blockIdx.x * blockDim.x + threadIdx.x;
    if (i >= N * D1) return;
    int n = i >> 8, c = i & 255;
    const float* xr = x + n * 6;
    float acc = 0.f;
#pragma unroll
    for (int k = 0; k < 6; ++k) acc += xr[k] * W[k * D1 + c];
    xb[i] = f2b(acc);
}

// Bt[c][k] = bf16(W2[k][c])
__global__ void k_cvtW(const float* __restrict__ W, unsigned short* __restrict__ Bt) {
    int c = blockIdx.x, k = threadIdx.x;
    Bt[c * D1 + k] = f2b(W[k * D1 + c]);
}

// alpha_s/alpha_d per (node, head) from bf16 features
__global__ void k_alpha(const unsigned short* __restrict__ xb, const float* __restrict__ av,
                        const float* __restrict__ dv, float* __restrict__ as_,
                        float* __restrict__ ad_, int N) {
    int i = blockIdx.x * blockDim.x + threadIdx.x;
    if (i >= N * HEADS) return;
    int n = i >> 2, h = i & 3;
    const unsigned short* row = xb + (size_t)n * D1 + h * HID;
    const float* a = av + h * HID;
    const float* d = dv + h * HID;
    float s = 0.f, t = 0.f;
#pragma unroll 4
    for (int j = 0; j < HID; j += 4) {
        ushort4 u = *(const ushort4*)(row + j);
        float f0 = b2f(u.x), f1 = b2f(u.y), f2 = b2f(u.z), f3 = b2f(u.w);
        s += f0 * a[j] + f1 * a[j + 1] + f2 * a[j + 2] + f3 * a[j + 3];
        t += f0 * d[j] + f1 * d[j + 1] + f2 * d[j + 2] + f3 * d[j + 3];
    }
    as_[i] = s; ad_[i] = t;
}

// ---------------- fused GAT aggregate: one wave per dst ----------------
template <bool BF16OUT>
__global__ void k_aggr(const int* __restrict__ rowp, const int* __restrict__ csrc,
                       const float* __restrict__ as_, const float* __restrict__ ad_,
                       const unsigned short* __restrict__ xb, const float* __restrict__ bias,
                       float* __restrict__ outf, unsigned short* __restrict__ outb, int N) {
    int d = blockIdx.x * 4 + (threadIdx.x >> 6);
    if (d >= N) return;
    int t = threadIdx.x & 63;
    int h = t >> 4;
    int lo = rowp[d], hi = rowp[d + 1];
    float adh = ad_[d * HEADS + h];

    // phase 1: per-head max
    float mx = -INFINITY;
    for (int k = lo + (t & 15); k < hi; k += 16) {
        int s = csrc[k];
        float v = as_[s * HEADS + h] + adh;
        v = v > 0.f ? v : NEG * v;
        mx = fmaxf(mx, v);
    }
#pragma unroll
    for (int off = 1; off < 16; off <<= 1) mx = fmaxf(mx, __shfl_xor(mx, off));

    // phase 2: exp-weighted accumulate + denominator
    float4 acc = {0.f, 0.f, 0.f, 0.f};
    float den = 0.f;
    int k = lo;
    for (; k + 1 < hi; k += 2) {
        int s0 = csrc[k], s1 = csrc[k + 1];
        float v0 = as_[s0 * HEADS + h] + adh;
        float v1 = as_[s1 * HEADS + h] + adh;
        v0 = v0 > 0.f ? v0 : NEG * v0;
        v1 = v1 > 0.f ? v1 : NEG * v1;
        float e0 = __expf(v0 - mx);
        float e1 = __expf(v1 - mx);
        ushort4 u0 = ((const ushort4*)(xb + (size_t)s0 * D1))[t];
        ushort4 u1 = ((const ushort4*)(xb + (size_t)s1 * D1))[t];
        den += e0 + e1;
        acc.x += e0 * b2f(u0.x) + e1 * b2f(u1.x);
        acc.y += e0 * b2f(u0.y) + e1 * b2f(u1.y);
        acc.z += e0 * b2f(u0.z) + e1 * b2f(u1.z);
        acc.w += e0 * b2f(u0.w) + e1 * b2f(u1.w);
    }
    if (k < hi) {
        int s0 = csrc[k];
        float v0 = as_[s0 * HEADS + h] + adh;
        v0 = v0 > 0.f ? v0 : NEG * v0;
        float e0 = __expf(v0 - mx);
        ushort4 u0 = ((const ushort4*)(xb + (size_t)s0 * D1))[t];
        den += e0;
        acc.x += e0 * b2f(u0.x); acc.y += e0 * b2f(u0.y);
        acc.z += e0 * b2f(u0.z); acc.w += e0 * b2f(u0.w);
    }
    float inv = 1.f / (den + 1e-16f);
    float4 bv = ((const float4*)bias)[t];
    float4 o;
    o.x = acc.x * inv + bv.x;
    o.y = acc.y * inv + bv.y;
    o.z = acc.z * inv + bv.z;
    o.w = acc.w * inv + bv.w;
    o.x = o.x > 0.f ? o.x : (__expf(o.x) - 1.f);
    o.y = o.y > 0.f ? o.y : (__expf(o.y) - 1.f);
    o.z = o.z > 0.f ? o.z : (__expf(o.z) - 1.f);
    o.w = o.w > 0.f ? o.w : (__expf(o.w) - 1.f);
    if (BF16OUT) {
        ushort4 ub; ub.x = f2b(o.x); ub.y = f2b(o.y); ub.z = f2b(o.z); ub.w = f2b(o.w);
        ((ushort4*)(outb + (size_t)d * D1))[t] = ub;
    } else {
        ((float4*)(outf + (size_t)d * D1))[t] = o;
    }
}

// ---------------- bf16 MFMA GEMM: xb2 = hb @ W2 ----------------
// A: hb [N][256] bf16 row-major; Bt [col][k] bf16; C: [N][256] bf16
__global__ void k_mm(const unsigned short* __restrict__ A, const unsigned short* __restrict__ Bt,
                     unsigned short* __restrict__ C, int N) {
    int w = threadIdx.x >> 6;
    int l = threadIdx.x & 63;
    int r0 = blockIdx.x * 64 + w * 16;
    int cy = blockIdx.y * 128;
    int lr = l & 15;
    int lk = (l >> 4) * 8;
    int arow = r0 + lr; if (arow >= N) arow = N - 1;
    const unsigned short* ap = A + (size_t)arow * D1 + lk;
    f32x4 acc[8];
#pragma unroll
    for (int i = 0; i < 8; ++i) acc[i] = (f32x4){0.f, 0.f, 0.f, 0.f};
    for (int ks = 0; ks < 8; ++ks) {
        bf16x8 av = *(const bf16x8*)(ap + ks * 32);
#pragma unroll
        for (int ct = 0; ct < 8; ++ct) {
            bf16x8 bv = *(const bf16x8*)(Bt + (size_t)(cy + ct * 16 + lr) * D1 + ks * 32 + lk);
            acc[ct] = __builtin_amdgcn_mfma_f32_16x16x32_bf16(av, bv, acc[ct], 0, 0, 0);
        }
    }
    int rbase = r0 + (l >> 4) * 4;
#pragma unroll
    for (int ct = 0; ct < 8; ++ct) {
#pragma unroll
        for (int r = 0; r < 4; ++r) {
            int row = rbase + r;
            if (row < N) C[(size_t)row * D1 + cy + ct * 16 + lr] = f2b(acc[ct][r]);
        }
    }
}

// ---------------- mean pool: one block per graph, batch sorted ----------------
__global__ void k_pool2(const float* __restrict__ h, const int* __restrict__ batch,
                        float* __restrict__ pooled, int N) {
    int g = blockIdx.x;
    int lo = 0, hi = N;
    while (lo < hi) { int m = (lo + hi) >> 1; if (batch[m] < g) lo = m + 1; else hi = m; }
    int lo2 = lo, hi2 = N;
    while (lo2 < hi2) { int m = (lo2 + hi2) >> 1; if (batch[m] < g + 1) lo2 = m + 1; else hi2 = m; }
    int c = threadIdx.x;
    float s = 0.f;
    for (int n = lo; n < lo2; ++n) s += h[(size_t)n * D1 + c];
    pooled[(size_t)g * D1 + c] = s / (float)max(lo2 - lo, 1);
}

// ---------------- KAN ----------------

__device__ inline float knotf(int j) { return (j - 3) * 0.4f - 1.0f; }

__device__ inline void bspl8(float x, float* out) {
    float t[12];
#pragma unroll
    for (int j = 0; j < 12; ++j) t[j] = knotf(j);
    float bb[11];
#pragma unroll
    for (int j = 0; j < 11; ++j) bb[j] = (x >= t[j] && x < t[j + 1]) ? 1.f : 0.f;
#pragma unroll
    for (int k = 1; k <= 3; ++k) {
#pragma unroll
        for (int j = 0; j + k < 11; ++j) {
            float dl = t[j + k] - t[j];
            float dr = t[j + k + 1] - t[j + 1];
            bb[j] = (x - t[j]) / dl * bb[j] + (t[j + k + 1] - x) / dr * bb[j + 1];
        }
    }
#pragma unroll
    for (int p = 0; p < 8; ++p) out[p] = bb[p];
}

__device__ inline float siluf(float x) { return x / (1.f + __expf(-x)); }

// fused KAN: one block per graph; pooled already holds the mean
__global__ void k_kan(const float* __restrict__ pooled,
                      const float* __restrict__ bw1, const float* __restrict__ sw1,
                      const float* __restrict__ sc1, const float* __restrict__ bw2,
                      const float* __restrict__ sw2, const float* __restrict__ sc2,
                      float* __restrict__ out) {
    __shared__ float sB[D1][9];
    __shared__ float sS[D1];
    __shared__ float sZ[32];
    int g = blockIdx.x;
    int i = threadIdx.x;
    float xi = pooled[(size_t)g * D1 + i];
    float b[8];
    bspl8(xi, b);
#pragma unroll
    for (int p = 0; p < 8; ++p) sB[i][p] = b[p];
    sS[i] = siluf(xi);
    __syncthreads();
    int wv = i >> 6, l = i & 63;
    for (int oo = 0; oo < 8; ++oo) {
        int o = wv * 8 + oo;
        float part = 0.f;
        for (int ii = l; ii < D1; ii += 64) {
            float sc = sc1[o * D1 + ii];
            float p0 = sS[ii] * bw1[o * D1 + ii];
            const float* sw = sw1 + ((size_t)o * D1 + ii) * 8;
#pragma unroll
            for (int p = 0; p < 8; ++p) p0 += sB[ii][p] * sw[p] * sc;
            part += p0;
        }
#pragma unroll
        for (int off = 32; off >= 1; off >>= 1) part += __shfl_down(part, off);
        if (l == 0) sZ[o] = part;
    }
    __syncthreads();
    if (i < 64) {
        float part = 0.f;
        if (i < 32) {
            float z = sZ[i];
            float b2[8];
            bspl8(z, b2);
            part = siluf(z) * bw2[i];
            float sc = sc2[i];
#pragma unroll
            for (int p = 0; p < 8; ++p) part += b2[p] * sw2[i * 8 + p] * sc;
        }
#pragma unroll
        for (int off = 32; off >= 1; off >>= 1) part += __shfl_down(part, off);
        if (i == 0) out[g] = part;
    }
}

extern "C" void kernel_launch(void* const* d_in, const int* in_sizes, int n_in,
                              void* d_out, int out_size, void* d_ws, size_t ws_size,
                              hipStream_t stream) {
    const float* x      = (const float*)d_in[0];
    const int*   ei     = (const int*)d_in[1];
    const int*   batch  = (const int*)d_in[2];
    const float* W1     = (const float*)d_in[3];
    const float* asrc1  = (const float*)d_in[4];
    const float* adst1  = (const float*)d_in[5];
    const float* b1     = (const float*)d_in[6];
    const float* W2     = (const float*)d_in[7];
    const float* asrc2  = (const float*)d_in[8];
    const float* adst2  = (const float*)d_in[9];
    const float* b2     = (const float*)d_in[10];
    const float* bw1    = (const float*)d_in[11];
    const float* sw1    = (const float*)d_in[12];
    const float* sc1    = (const float*)d_in[13];
    const float* bw2    = (const float*)d_in[14];
    const float* sw2    = (const float*)d_in[15];
    const float* sc2    = (const float*)d_in[16];
    float* outp = (float*)d_out;

    const int N  = in_sizes[0] / 6;
    const int E  = in_sizes[1] / 2;
    const int ET = E + N;

    char* base = (char*)d_ws;
    unsigned short* xb = (unsigned short*)base;   base += (size_t)N * D1 * 2;   // bf16 features
    unsigned short* hb = (unsigned short*)base;   base += (size_t)N * D1 * 2;   // bf16 layer-1 out
    float* h2     = (float*)base;                 base += (size_t)N * D1 * 4;   // fp32 layer-2 out
    float* as_    = (float*)base;                 base += (size_t)N * HEADS * 4;
    float* ad_    = (float*)base;                 base += (size_t)N * HEADS * 4;
    float* pooled = (float*)base;                 base += (size_t)NGR * D1 * 4;
    unsigned short* Btb = (unsigned short*)base;  base += (size_t)D1 * D1 * 2;
    int* deg  = (int*)base;                       base += (size_t)N * 4;
    int* fill = (int*)base;                       base += (size_t)N * 4;
    int* rowp = (int*)base;                       base += (size_t)(N + 1) * 4;
    int* csrc = (int*)base;                       base += (size_t)ET * 4;

    const int TB = 256;
    int gNC = cdiv(N * D1, TB);
    int gNH = cdiv(N * HEADS, TB);
    int gET = cdiv(ET, TB);
    int gAG = cdiv(N, 4);

    // ---------------- CSR build ----------------
    hipMemsetAsync(deg, 0, (size_t)N * sizeof(int), stream);
    hipMemsetAsync(fill, 0, (size_t)N * sizeof(int), stream);
    k_deg<<<gET, TB, 0, stream>>>(ei, E, ET, deg);
    k_scan<<<1, 1024, 0, stream>>>(deg, rowp, N);
    k_scatter<<<gET, TB, 0, stream>>>(ei, E, ET, rowp, fill, csrc);
    k_cvtW<<<D1, D1, 0, stream>>>(W2, Btb);

    // ---------------- layer 1 ----------------
    k_xw1<<<gNC, TB, 0, stream>>>(x, W1, xb, N);
    k_alpha<<<gNH, TB, 0, stream>>>(xb, asrc1, adst1, as_, ad_, N);
    k_aggr<true><<<gAG, TB, 0, stream>>>(rowp, csrc, as_, ad_, xb, b1, nullptr, hb, N);

    // ---------------- layer 2 ----------------
    k_mm<<<dim3(cdiv(N, 64), 2), TB, 0, stream>>>(hb, Btb, xb, N);
    k_alpha<<<gNH, TB, 0, stream>>>(xb, asrc2, adst2, as_, ad_, N);
    k_aggr<false><<<gAG, TB, 0, stream>>>(rowp, csrc, as_, ad_, xb, b2, h2, nullptr, N);

    // ---------------- pool + KAN ----------------
    k_pool2<<<NGR, TB, 0, stream>>>(h2, batch, pooled, N);
    k_kan<<<NGR, TB, 0, stream>>>(pooled, bw1, sw1, sc1, bw2, sw2, sc2, outp);
}

// Round 4
// 385.399 us; speedup vs baseline: 16.3321x; 1.3081x over previous
//
#include <hip/hip_runtime.h>
#include <math.h>

#define HEADS 4
#define HID 64
#define D1 256
#define NGR 1024
#define NEG 0.2f

typedef __attribute__((ext_vector_type(8))) short bf16x8;
typedef __attribute__((ext_vector_type(4))) float f32x4;

static inline int cdiv(int a, int b) { return (a + b - 1) / b; }

__device__ inline unsigned short f2b(float f) {
    union { float f; unsigned u; } v; v.f = f;
    unsigned r = v.u + 0x7FFFu + ((v.u >> 16) & 1u);
    return (unsigned short)(r >> 16);
}
__device__ inline float b2f(unsigned short u) {
    union { unsigned u; float f; } v; v.u = ((unsigned)u) << 16;
    return v.f;
}

// ---------------- CSR build ----------------

__global__ void k_deg(const int* __restrict__ ei, int E, int ET, int* __restrict__ deg) {
    int e = blockIdx.x * blockDim.x + threadIdx.x;
    if (e >= ET) return;
    int d = (e < E) ? ei[E + e] : e - E;
    atomicAdd(&deg[d], 1);
}

__global__ void k_scan(const int* __restrict__ deg, int* __restrict__ rowp, int N) {
    __shared__ int ssum[1024];
    int t = threadIdx.x;
    int chunk = (N + 1023) / 1024;
    int lo = t * chunk, hi = min(lo + chunk, N);
    int s = 0;
    for (int i = lo; i < hi; ++i) s += deg[i];
    ssum[t] = s;
    __syncthreads();
    for (int off = 1; off < 1024; off <<= 1) {
        int v = 0;
        if (t >= off) v = ssum[t - off];
        __syncthreads();
        ssum[t] += v;
        __syncthreads();
    }
    int run = ssum[t] - s;
    for (int i = lo; i < hi; ++i) { rowp[i] = run; run += deg[i]; }
    if (t == 1023) rowp[N] = ssum[1023];
}

__global__ void k_scatter(const int* __restrict__ ei, int E, int ET,
                          const int* __restrict__ rowp, int* __restrict__ fill,
                          int* __restrict__ csrc) {
    int e = blockIdx.x * blockDim.x + threadIdx.x;
    if (e >= ET) return;
    int s, d;
    if (e < E) { s = ei[e]; d = ei[E + e]; } else { s = d = e - E; }
    int pos = rowp[d] + atomicAdd(&fill[d], 1);
    csrc[pos] = s;
}

// ---------------- prep: va1[k][h8] = W1-slice @ a1  (h8: 0-3 src, 4-7 dst) ----------------
__global__ void k_prep(const float* __restrict__ W1, const float* __restrict__ asrc1,
                       const float* __restrict__ adst1, float* __restrict__ va1) {
    int id = threadIdx.x;
    if (id >= 48) return;
    int k = id / 8, h8 = id % 8;
    int h = h8 & 3;
    const float* avec = (h8 < 4) ? (asrc1 + h * HID) : (adst1 + h * HID);
    const float* wrow = W1 + k * D1 + h * HID;
    float s = 0.f;
#pragma unroll 8
    for (int j = 0; j < HID; ++j) s += wrow[j] * avec[j];
    va1[k * 8 + h8] = s;
}

// Bt_ext[272][256]: rows 0..255 = W2^T; 256..259 = W2@a_src2(h); 260..263 = W2@a_dst2(h); 264..271 = 0
__global__ void k_cvtW(const float* __restrict__ W, const float* __restrict__ asrc2,
                       const float* __restrict__ adst2, unsigned short* __restrict__ Bt) {
    int c = blockIdx.x, k = threadIdx.x;
    float v;
    if (c < 256) {
        v = W[k * D1 + c];
    } else if (c < 264) {
        int h = (c - 256) & 3;
        const float* avec = (c < 260) ? (asrc2 + h * HID) : (adst2 + h * HID);
        const float* wrow = W + k * D1 + h * HID;
        float s = 0.f;
#pragma unroll 8
        for (int j = 0; j < HID; ++j) s += wrow[j] * avec[j];
        v = s;
    } else {
        v = 0.f;
    }
    Bt[c * D1 + k] = f2b(v);
}

// layer-1 alphas: as/ad[n,h] = x[n,:6] . va1[:,h]
__global__ void k_alpha1(const float* __restrict__ x, const float* __restrict__ va1,
                         float* __restrict__ as_, float* __restrict__ ad_, int N) {
    int n = blockIdx.x * blockDim.x + threadIdx.x;
    if (n >= N) return;
    float2 x01 = *(const float2*)(x + n * 6);
    float2 x23 = *(const float2*)(x + n * 6 + 2);
    float2 x45 = *(const float2*)(x + n * 6 + 4);
    float xv[6] = {x01.x, x01.y, x23.x, x23.y, x45.x, x45.y};
    float4 sv, dv;
#pragma unroll
    for (int h = 0; h < 4; ++h) {
        float s = 0.f, d = 0.f;
#pragma unroll
        for (int k = 0; k < 6; ++k) {
            s += xv[k] * va1[k * 8 + h];
            d += xv[k] * va1[k * 8 + 4 + h];
        }
        (&sv.x)[h] = s; (&dv.x)[h] = d;
    }
    ((float4*)as_)[n] = sv;
    ((float4*)ad_)[n] = dv;
}

// ---------------- layer-1 fused aggregate: 16 lanes per dst ----------------
// acc[h][k<6] = sum_e exp(lrelu(as[s]+ad[d])-mx) * x[s][k]; out = (acc/den)@W1 + b1, ELU, bf16
__global__ void k_aggr1(const int* __restrict__ rowp, const int* __restrict__ csrc,
                        const float* __restrict__ as_, const float* __restrict__ ad_,
                        const float* __restrict__ x, const float* __restrict__ W1,
                        const float* __restrict__ b1, unsigned short* __restrict__ outb, int N) {
    int d = blockIdx.x * 16 + (threadIdx.x >> 4);
    if (d >= N) return;
    int q = threadIdx.x & 15;
    int lo = rowp[d], hi = rowp[d + 1];
    float4 adv = ((const float4*)ad_)[d];

    // phase 1: per-head max over edges
    float mx0 = -INFINITY, mx1 = -INFINITY, mx2 = -INFINITY, mx3 = -INFINITY;
    for (int k = lo + q; k < hi; k += 16) {
        int s = csrc[k];
        float4 av = ((const float4*)as_)[s];
        float l0 = av.x + adv.x; l0 = l0 > 0.f ? l0 : NEG * l0;
        float l1 = av.y + adv.y; l1 = l1 > 0.f ? l1 : NEG * l1;
        float l2 = av.z + adv.z; l2 = l2 > 0.f ? l2 : NEG * l2;
        float l3 = av.w + adv.w; l3 = l3 > 0.f ? l3 : NEG * l3;
        mx0 = fmaxf(mx0, l0); mx1 = fmaxf(mx1, l1);
        mx2 = fmaxf(mx2, l2); mx3 = fmaxf(mx3, l3);
    }
#pragma unroll
    for (int off = 1; off < 16; off <<= 1) {
        mx0 = fmaxf(mx0, __shfl_xor(mx0, off));
        mx1 = fmaxf(mx1, __shfl_xor(mx1, off));
        mx2 = fmaxf(mx2, __shfl_xor(mx2, off));
        mx3 = fmaxf(mx3, __shfl_xor(mx3, off));
    }

    // phase 2: accumulate per-head 6-dim messages
    float a[4][6];
#pragma unroll
    for (int h = 0; h < 4; ++h)
#pragma unroll
        for (int k = 0; k < 6; ++k) a[h][k] = 0.f;
    float den0 = 0.f, den1 = 0.f, den2 = 0.f, den3 = 0.f;
    for (int k = lo + q; k < hi; k += 16) {
        int s = csrc[k];
        float4 av = ((const float4*)as_)[s];
        float l0 = av.x + adv.x; l0 = l0 > 0.f ? l0 : NEG * l0;
        float l1 = av.y + adv.y; l1 = l1 > 0.f ? l1 : NEG * l1;
        float l2 = av.z + adv.z; l2 = l2 > 0.f ? l2 : NEG * l2;
        float l3 = av.w + adv.w; l3 = l3 > 0.f ? l3 : NEG * l3;
        float e0 = __expf(l0 - mx0);
        float e1 = __expf(l1 - mx1);
        float e2 = __expf(l2 - mx2);
        float e3 = __expf(l3 - mx3);
        den0 += e0; den1 += e1; den2 += e2; den3 += e3;
        float2 x01 = *(const float2*)(x + s * 6);
        float2 x23 = *(const float2*)(x + s * 6 + 2);
        float2 x45 = *(const float2*)(x + s * 6 + 4);
        float xv[6] = {x01.x, x01.y, x23.x, x23.y, x45.x, x45.y};
#pragma unroll
        for (int kk = 0; kk < 6; ++kk) {
            a[0][kk] += e0 * xv[kk];
            a[1][kk] += e1 * xv[kk];
            a[2][kk] += e2 * xv[kk];
            a[3][kk] += e3 * xv[kk];
        }
    }
    // reduce across the 16-lane group
#pragma unroll
    for (int off = 1; off < 16; off <<= 1) {
        den0 += __shfl_xor(den0, off);
        den1 += __shfl_xor(den1, off);
        den2 += __shfl_xor(den2, off);
        den3 += __shfl_xor(den3, off);
#pragma unroll
        for (int h = 0; h < 4; ++h)
#pragma unroll
            for (int k = 0; k < 6; ++k) a[h][k] += __shfl_xor(a[h][k], off);
    }

    // epilogue: lane q computes cols [q*16, q*16+16); head h = q>>2 (uniform per lane)
    int h = q >> 2;
    float dh = (h == 0) ? den0 : (h == 1) ? den1 : (h == 2) ? den2 : den3;
    float inv = 1.f / (dh + 1e-16f);
    float m[6];
#pragma unroll
    for (int k = 0; k < 6; ++k)
        m[k] = (h == 0) ? a[0][k] : (h == 1) ? a[1][k] : (h == 2) ? a[2][k] : a[3][k];
    int c0 = q * 16;
    unsigned short ob[16];
#pragma unroll
    for (int cc = 0; cc < 16; ++cc) {
        int c = c0 + cc;
        float o = m[0] * W1[c] + m[1] * W1[D1 + c] + m[2] * W1[2 * D1 + c] +
                  m[3] * W1[3 * D1 + c] + m[4] * W1[4 * D1 + c] + m[5] * W1[5 * D1 + c];
        o = o * inv + b1[c];
        o = o > 0.f ? o : (__expf(o) - 1.f);
        ob[cc] = f2b(o);
    }
#pragma unroll
    for (int v = 0; v < 4; ++v)
        ((ushort4*)(outb + (size_t)d * D1 + c0))[v] =
            make_ushort4(ob[v * 4], ob[v * 4 + 1], ob[v * 4 + 2], ob[v * 4 + 3]);
}

// ---------------- bf16 MFMA GEMM: xb = hb @ W2 (+ alpha2 tile) ----------------
__global__ void k_mm(const unsigned short* __restrict__ A, const unsigned short* __restrict__ Bt,
                     unsigned short* __restrict__ C, float* __restrict__ as_,
                     float* __restrict__ ad_, int N) {
    int w = threadIdx.x >> 6;
    int l = threadIdx.x & 63;
    int r0 = blockIdx.x * 64 + w * 16;
    bool half0 = (blockIdx.y == 0);
    int cy = half0 ? 0 : 128;
    int lr = l & 15;
    int lk = (l >> 4) * 8;
    int arow = r0 + lr; if (arow >= N) arow = N - 1;
    const unsigned short* ap = A + (size_t)arow * D1 + lk;
    f32x4 acc[8];
    f32x4 accE = (f32x4){0.f, 0.f, 0.f, 0.f};
#pragma unroll
    for (int i = 0; i < 8; ++i) acc[i] = (f32x4){0.f, 0.f, 0.f, 0.f};
    for (int ks = 0; ks < 8; ++ks) {
        bf16x8 av = *(const bf16x8*)(ap + ks * 32);
#pragma unroll
        for (int ct = 0; ct < 8; ++ct) {
            bf16x8 bv = *(const bf16x8*)(Bt + (size_t)(cy + ct * 16 + lr) * D1 + ks * 32 + lk);
            acc[ct] = __builtin_amdgcn_mfma_f32_16x16x32_bf16(av, bv, acc[ct], 0, 0, 0);
        }
        if (half0) {
            bf16x8 bv = *(const bf16x8*)(Bt + (size_t)(256 + lr) * D1 + ks * 32 + lk);
            accE = __builtin_amdgcn_mfma_f32_16x16x32_bf16(av, bv, accE, 0, 0, 0);
        }
    }
    int rbase = r0 + (l >> 4) * 4;
#pragma unroll
    for (int ct = 0; ct < 8; ++ct) {
#pragma unroll
        for (int r = 0; r < 4; ++r) {
            int row = rbase + r;
            if (row < N) C[(size_t)row * D1 + cy + ct * 16 + lr] = f2b(acc[ct][r]);
        }
    }
    if (half0) {
#pragma unroll
        for (int r = 0; r < 4; ++r) {
            int row = rbase + r;
            if (row < N) {
                float v = accE[r];
                if (lr < 4) as_[row * HEADS + lr] = v;
                else if (lr < 8) ad_[row * HEADS + (lr - 4)] = v;
            }
        }
    }
}

// ---------------- layer-2 aggregate: one wave per dst, bf16 gather ----------------
__global__ void k_aggr2(const int* __restrict__ rowp, const int* __restrict__ csrc,
                        const float* __restrict__ as_, const float* __restrict__ ad_,
                        const unsigned short* __restrict__ xb, const float* __restrict__ bias,
                        unsigned short* __restrict__ outb, int N) {
    int d = blockIdx.x * 4 + (threadIdx.x >> 6);
    if (d >= N) return;
    int t = threadIdx.x & 63;
    int h = t >> 4;
    int lo = rowp[d], hi = rowp[d + 1];
    float adh = ad_[d * HEADS + h];

    float mx = -INFINITY;
    for (int k = lo + (t & 15); k < hi; k += 16) {
        int s = csrc[k];
        float v = as_[s * HEADS + h] + adh;
        v = v > 0.f ? v : NEG * v;
        mx = fmaxf(mx, v);
    }
#pragma unroll
    for (int off = 1; off < 16; off <<= 1) mx = fmaxf(mx, __shfl_xor(mx, off));

    float4 acc = {0.f, 0.f, 0.f, 0.f};
    float den = 0.f;
    int k = lo;
    for (; k + 3 < hi; k += 4) {
        int s0 = csrc[k], s1 = csrc[k + 1], s2 = csrc[k + 2], s3 = csrc[k + 3];
        float v0 = as_[s0 * HEADS + h] + adh; v0 = v0 > 0.f ? v0 : NEG * v0;
        float v1 = as_[s1 * HEADS + h] + adh; v1 = v1 > 0.f ? v1 : NEG * v1;
        float v2 = as_[s2 * HEADS + h] + adh; v2 = v2 > 0.f ? v2 : NEG * v2;
        float v3 = as_[s3 * HEADS + h] + adh; v3 = v3 > 0.f ? v3 : NEG * v3;
        float e0 = __expf(v0 - mx), e1 = __expf(v1 - mx);
        float e2 = __expf(v2 - mx), e3 = __expf(v3 - mx);
        ushort4 u0 = ((const ushort4*)(xb + (size_t)s0 * D1))[t];
        ushort4 u1 = ((const ushort4*)(xb + (size_t)s1 * D1))[t];
        ushort4 u2 = ((const ushort4*)(xb + (size_t)s2 * D1))[t];
        ushort4 u3 = ((const ushort4*)(xb + (size_t)s3 * D1))[t];
        den += e0 + e1 + e2 + e3;
        acc.x += e0 * b2f(u0.x) + e1 * b2f(u1.x) + e2 * b2f(u2.x) + e3 * b2f(u3.x);
        acc.y += e0 * b2f(u0.y) + e1 * b2f(u1.y) + e2 * b2f(u2.y) + e3 * b2f(u3.y);
        acc.z += e0 * b2f(u0.z) + e1 * b2f(u1.z) + e2 * b2f(u2.z) + e3 * b2f(u3.z);
        acc.w += e0 * b2f(u0.w) + e1 * b2f(u1.w) + e2 * b2f(u2.w) + e3 * b2f(u3.w);
    }
    for (; k < hi; ++k) {
        int s0 = csrc[k];
        float v0 = as_[s0 * HEADS + h] + adh; v0 = v0 > 0.f ? v0 : NEG * v0;
        float e0 = __expf(v0 - mx);
        ushort4 u0 = ((const ushort4*)(xb + (size_t)s0 * D1))[t];
        den += e0;
        acc.x += e0 * b2f(u0.x); acc.y += e0 * b2f(u0.y);
        acc.z += e0 * b2f(u0.z); acc.w += e0 * b2f(u0.w);
    }
    float inv = 1.f / (den + 1e-16f);
    float4 bv = ((const float4*)bias)[t];
    float4 o;
    o.x = acc.x * inv + bv.x;
    o.y = acc.y * inv + bv.y;
    o.z = acc.z * inv + bv.z;
    o.w = acc.w * inv + bv.w;
    o.x = o.x > 0.f ? o.x : (__expf(o.x) - 1.f);
    o.y = o.y > 0.f ? o.y : (__expf(o.y) - 1.f);
    o.z = o.z > 0.f ? o.z : (__expf(o.z) - 1.f);
    o.w = o.w > 0.f ? o.w : (__expf(o.w) - 1.f);
    ushort4 ub; ub.x = f2b(o.x); ub.y = f2b(o.y); ub.z = f2b(o.z); ub.w = f2b(o.w);
    ((ushort4*)(outb + (size_t)d * D1))[t] = ub;
}

// ---------------- fused mean-pool + KAN: one block per graph ----------------

__device__ inline float knotf(int j) { return (j - 3) * 0.4f - 1.0f; }

__device__ inline void bspl8(float x, float* out) {
    float t[12];
#pragma unroll
    for (int j = 0; j < 12; ++j) t[j] = knotf(j);
    float bb[11];
#pragma unroll
    for (int j = 0; j < 11; ++j) bb[j] = (x >= t[j] && x < t[j + 1]) ? 1.f : 0.f;
#pragma unroll
    for (int k = 1; k <= 3; ++k) {
#pragma unroll
        for (int j = 0; j + k < 11; ++j) {
            float dl = t[j + k] - t[j];
            float dr = t[j + k + 1] - t[j + 1];
            bb[j] = (x - t[j]) / dl * bb[j] + (t[j + k + 1] - x) / dr * bb[j + 1];
        }
    }
#pragma unroll
    for (int p = 0; p < 8; ++p) out[p] = bb[p];
}

__device__ inline float siluf(float x) { return x / (1.f + __expf(-x)); }

__global__ void k_poolkan(const unsigned short* __restrict__ hb2, const int* __restrict__ batch,
                          const float* __restrict__ bw1, const float* __restrict__ sw1,
                          const float* __restrict__ sc1, const float* __restrict__ bw2,
                          const float* __restrict__ sw2, const float* __restrict__ sc2,
                          float* __restrict__ out, int N) {
    __shared__ float sB[D1][9];
    __shared__ float sS[D1];
    __shared__ float sZ[32];
    int g = blockIdx.x;
    int lo = 0, hi = N;
    while (lo < hi) { int m = (lo + hi) >> 1; if (batch[m] < g) lo = m + 1; else hi = m; }
    int lo2 = lo, hi2 = N;
    while (lo2 < hi2) { int m = (lo2 + hi2) >> 1; if (batch[m] < g + 1) lo2 = m + 1; else hi2 = m; }
    int i = threadIdx.x;
    float s = 0.f;
    for (int n = lo; n < lo2; ++n) s += b2f(hb2[(size_t)n * D1 + i]);
    float xi = s / (float)max(lo2 - lo, 1);
    float b[8];
    bspl8(xi, b);
#pragma unroll
    for (int p = 0; p < 8; ++p) sB[i][p] = b[p];
    sS[i] = siluf(xi);
    __syncthreads();
    int wv = i >> 6, l = i & 63;
    for (int oo = 0; oo < 8; ++oo) {
        int o = wv * 8 + oo;
        float part = 0.f;
        for (int ii = l; ii < D1; ii += 64) {
            float sc = sc1[o * D1 + ii];
            float p0 = sS[ii] * bw1[o * D1 + ii];
            const float* sw = sw1 + ((size_t)o * D1 + ii) * 8;
#pragma unroll
            for (int p = 0; p < 8; ++p) p0 += sB[ii][p] * sw[p] * sc;
            part += p0;
        }
#pragma unroll
        for (int off = 32; off >= 1; off >>= 1) part += __shfl_down(part, off);
        if (l == 0) sZ[o] = part;
    }
    __syncthreads();
    if (i < 64) {
        float part = 0.f;
        if (i < 32) {
            float z = sZ[i];
            float b2a[8];
            bspl8(z, b2a);
            part = siluf(z) * bw2[i];
            float sc = sc2[i];
#pragma unroll
            for (int p = 0; p < 8; ++p) part += b2a[p] * sw2[i * 8 + p] * sc;
        }
#pragma unroll
        for (int off = 32; off >= 1; off >>= 1) part += __shfl_down(part, off);
        if (i == 0) out[g] = part;
    }
}

extern "C" void kernel_launch(void* const* d_in, const int* in_sizes, int n_in,
                              void* d_out, int out_size, void* d_ws, size_t ws_size,
                              hipStream_t stream) {
    const float* x      = (const float*)d_in[0];
    const int*   ei     = (const int*)d_in[1];
    const int*   batch  = (const int*)d_in[2];
    const float* W1     = (const float*)d_in[3];
    const float* asrc1  = (const float*)d_in[4];
    const float* adst1  = (const float*)d_in[5];
    const float* b1     = (const float*)d_in[6];
    const float* W2     = (const float*)d_in[7];
    const float* asrc2  = (const float*)d_in[8];
    const float* adst2  = (const float*)d_in[9];
    const float* b2     = (const float*)d_in[10];
    const float* bw1    = (const float*)d_in[11];
    const float* sw1    = (const float*)d_in[12];
    const float* sc1    = (const float*)d_in[13];
    const float* bw2    = (const float*)d_in[14];
    const float* sw2    = (const float*)d_in[15];
    const float* sc2    = (const float*)d_in[16];
    float* outp = (float*)d_out;

    const int N  = in_sizes[0] / 6;
    const int E  = in_sizes[1] / 2;
    const int ET = E + N;

    char* base = (char*)d_ws;
    unsigned short* hb  = (unsigned short*)base; base += (size_t)N * D1 * 2;  // layer-1 out (bf16)
    unsigned short* xb  = (unsigned short*)base; base += (size_t)N * D1 * 2;  // xw2 (bf16)
    unsigned short* hb2 = (unsigned short*)base; base += (size_t)N * D1 * 2;  // layer-2 out (bf16)
    float* as_ = (float*)base;                   base += (size_t)N * HEADS * 4;
    float* ad_ = (float*)base;                   base += (size_t)N * HEADS * 4;
    unsigned short* Btb = (unsigned short*)base; base += (size_t)272 * D1 * 2;
    float* va1 = (float*)base;                   base += 48 * 4;
    int* deg  = (int*)base;                      base += (size_t)N * 4;
    int* fill = (int*)base;                      base += (size_t)N * 4;
    int* rowp = (int*)base;                      base += (size_t)(N + 1) * 4;
    int* csrc = (int*)base;                      base += (size_t)ET * 4;

    const int TB = 256;
    int gET = cdiv(ET, TB);

    // CSR build + weight prep
    hipMemsetAsync(deg, 0, (size_t)N * sizeof(int), stream);
    hipMemsetAsync(fill, 0, (size_t)N * sizeof(int), stream);
    k_prep<<<1, 64, 0, stream>>>(W1, asrc1, adst1, va1);
    k_deg<<<gET, TB, 0, stream>>>(ei, E, ET, deg);
    k_scan<<<1, 1024, 0, stream>>>(deg, rowp, N);
    k_scatter<<<gET, TB, 0, stream>>>(ei, E, ET, rowp, fill, csrc);
    k_cvtW<<<272, 256, 0, stream>>>(W2, asrc2, adst2, Btb);

    // layer 1 (rank-6 aggregation)
    k_alpha1<<<cdiv(N, TB), TB, 0, stream>>>(x, va1, as_, ad_, N);
    k_aggr1<<<cdiv(N, 16), TB, 0, stream>>>(rowp, csrc, as_, ad_, x, W1, b1, hb, N);

    // layer 2
    k_mm<<<dim3(cdiv(N, 64), 2), TB, 0, stream>>>(hb, Btb, xb, as_, ad_, N);
    k_aggr2<<<cdiv(N, 4), TB, 0, stream>>>(rowp, csrc, as_, ad_, xb, b2, hb2, N);

    // pool + KAN
    k_poolkan<<<NGR, TB, 0, stream>>>(hb2, batch, bw1, sw1, sc1, bw2, sw2, sc2, outp, N);
}

// Round 5
// 307.614 us; speedup vs baseline: 20.4619x; 1.2529x over previous
//
#include <hip/hip_runtime.h>
#include <math.h>

#define HEADS 4
#define HID 64
#define D1 256
#define NGR 1024
#define NEG 0.2f

typedef __attribute__((ext_vector_type(8))) short bf16x8;
typedef __attribute__((ext_vector_type(4))) float f32x4;

static inline int cdiv(int a, int b) { return (a + b - 1) / b; }

__device__ inline unsigned short f2b(float f) {
    union { float f; unsigned u; } v; v.f = f;
    unsigned r = v.u + 0x7FFFu + ((v.u >> 16) & 1u);
    return (unsigned short)(r >> 16);
}
__device__ inline float b2f(unsigned short u) {
    union { unsigned u; float f; } v; v.u = ((unsigned)u) << 16;
    return v.f;
}

// ---------------- CSR build ----------------

__global__ void k_deg(const int* __restrict__ ei, int E, int ET, int* __restrict__ deg) {
    int e = blockIdx.x * blockDim.x + threadIdx.x;
    if (e >= ET) return;
    int d = (e < E) ? ei[E + e] : e - E;
    atomicAdd(&deg[d], 1);
}

// multi-block scan, phase 1: block-local exclusive scan over 256 elems of deg[0..N]
// (element N is a virtual 0 so rowp[N] lands the grand total); part[b] = block sum
__global__ void k_scan1(const int* __restrict__ deg, int* __restrict__ rowp,
                        int* __restrict__ part, int N) {
    __shared__ int sd[256];
    int t = threadIdx.x;
    int i = blockIdx.x * 256 + t;
    int v = (i < N) ? deg[i] : 0;
    sd[t] = v;
    __syncthreads();
    for (int off = 1; off < 256; off <<= 1) {
        int u = (t >= off) ? sd[t - off] : 0;
        __syncthreads();
        sd[t] += u;
        __syncthreads();
    }
    if (i <= N) rowp[i] = sd[t] - v;  // exclusive prefix within block
    if (t == 255) part[blockIdx.x] = sd[255];
}

// phase 2: exclusive scan of block partials (P <= 1024)
__global__ void k_scan2(int* __restrict__ part, int P) {
    __shared__ int sp[1024];
    int t = threadIdx.x;
    int v = (t < P) ? part[t] : 0;
    sp[t] = v;
    __syncthreads();
    for (int off = 1; off < 1024; off <<= 1) {
        int u = (t >= off) ? sp[t - off] : 0;
        __syncthreads();
        sp[t] += u;
        __syncthreads();
    }
    if (t < P) part[t] = sp[t] - v;
}

// phase 3: add block offsets
__global__ void k_scan3(int* __restrict__ rowp, const int* __restrict__ part, int NP1) {
    int i = blockIdx.x * 256 + threadIdx.x;
    if (i < NP1) rowp[i] += part[blockIdx.x];
}

__global__ void k_scatter(const int* __restrict__ ei, int E, int ET,
                          const int* __restrict__ rowp, int* __restrict__ fill,
                          int* __restrict__ csrc) {
    int e = blockIdx.x * blockDim.x + threadIdx.x;
    if (e >= ET) return;
    int s, d;
    if (e < E) { s = ei[e]; d = ei[E + e]; } else { s = d = e - E; }
    int pos = rowp[d] + atomicAdd(&fill[d], 1);
    csrc[pos] = s;
}

// ---------------- prep: va1[k][h8] = W1-slice @ a1  (h8: 0-3 src, 4-7 dst) ----------------
__global__ void k_prep(const float* __restrict__ W1, const float* __restrict__ asrc1,
                       const float* __restrict__ adst1, float* __restrict__ va1) {
    int id = threadIdx.x;
    if (id >= 48) return;
    int k = id / 8, h8 = id % 8;
    int h = h8 & 3;
    const float* avec = (h8 < 4) ? (asrc1 + h * HID) : (adst1 + h * HID);
    const float* wrow = W1 + k * D1 + h * HID;
    float s = 0.f;
#pragma unroll 8
    for (int j = 0; j < HID; ++j) s += wrow[j] * avec[j];
    va1[k * 8 + h8] = s;
}

// Bt_ext[272][256]: rows 0..255 = W2^T; 256..259 = W2@a_src2(h); 260..263 = W2@a_dst2(h); 264..271 = 0
__global__ void k_cvtW(const float* __restrict__ W, const float* __restrict__ asrc2,
                       const float* __restrict__ adst2, unsigned short* __restrict__ Bt) {
    int c = blockIdx.x, k = threadIdx.x;
    float v;
    if (c < 256) {
        v = W[k * D1 + c];
    } else if (c < 264) {
        int h = (c - 256) & 3;
        const float* avec = (c < 260) ? (asrc2 + h * HID) : (adst2 + h * HID);
        const float* wrow = W + k * D1 + h * HID;
        float s = 0.f;
#pragma unroll 8
        for (int j = 0; j < HID; ++j) s += wrow[j] * avec[j];
        v = s;
    } else {
        v = 0.f;
    }
    Bt[c * D1 + k] = f2b(v);
}

// layer-1 alphas: as/ad[n,h] = x[n,:6] . va1[:,h]
__global__ void k_alpha1(const float* __restrict__ x, const float* __restrict__ va1,
                         float* __restrict__ as_, float* __restrict__ ad_, int N) {
    int n = blockIdx.x * blockDim.x + threadIdx.x;
    if (n >= N) return;
    float2 x01 = *(const float2*)(x + n * 6);
    float2 x23 = *(const float2*)(x + n * 6 + 2);
    float2 x45 = *(const float2*)(x + n * 6 + 4);
    float xv[6] = {x01.x, x01.y, x23.x, x23.y, x45.x, x45.y};
    float4 sv, dv;
#pragma unroll
    for (int h = 0; h < 4; ++h) {
        float s = 0.f, d = 0.f;
#pragma unroll
        for (int k = 0; k < 6; ++k) {
            s += xv[k] * va1[k * 8 + h];
            d += xv[k] * va1[k * 8 + 4 + h];
        }
        (&sv.x)[h] = s; (&dv.x)[h] = d;
    }
    ((float4*)as_)[n] = sv;
    ((float4*)ad_)[n] = dv;
}

// ---------------- layer-1 fused aggregate: 16 lanes per dst, no-max softmax ----------------
__global__ void k_aggr1(const int* __restrict__ rowp, const int* __restrict__ csrc,
                        const float* __restrict__ as_, const float* __restrict__ ad_,
                        const float* __restrict__ x, const float* __restrict__ W1,
                        const float* __restrict__ b1, unsigned short* __restrict__ outb, int N) {
    int d = blockIdx.x * 16 + (threadIdx.x >> 4);
    if (d >= N) return;
    int q = threadIdx.x & 15;
    int lo = rowp[d], hi = rowp[d + 1];
    float4 adv = ((const float4*)ad_)[d];

    // single pass: exp(lrelu(v)) weighted accumulate (softmax shift-invariant, |v| small)
    float a[4][6];
#pragma unroll
    for (int h = 0; h < 4; ++h)
#pragma unroll
        for (int k = 0; k < 6; ++k) a[h][k] = 0.f;
    float den0 = 0.f, den1 = 0.f, den2 = 0.f, den3 = 0.f;
    for (int k = lo + q; k < hi; k += 16) {
        int s = csrc[k];
        float4 av = ((const float4*)as_)[s];
        float l0 = av.x + adv.x; l0 = l0 > 0.f ? l0 : NEG * l0;
        float l1 = av.y + adv.y; l1 = l1 > 0.f ? l1 : NEG * l1;
        float l2 = av.z + adv.z; l2 = l2 > 0.f ? l2 : NEG * l2;
        float l3 = av.w + adv.w; l3 = l3 > 0.f ? l3 : NEG * l3;
        float e0 = __expf(l0);
        float e1 = __expf(l1);
        float e2 = __expf(l2);
        float e3 = __expf(l3);
        den0 += e0; den1 += e1; den2 += e2; den3 += e3;
        float2 x01 = *(const float2*)(x + s * 6);
        float2 x23 = *(const float2*)(x + s * 6 + 2);
        float2 x45 = *(const float2*)(x + s * 6 + 4);
        float xv[6] = {x01.x, x01.y, x23.x, x23.y, x45.x, x45.y};
#pragma unroll
        for (int kk = 0; kk < 6; ++kk) {
            a[0][kk] += e0 * xv[kk];
            a[1][kk] += e1 * xv[kk];
            a[2][kk] += e2 * xv[kk];
            a[3][kk] += e3 * xv[kk];
        }
    }
#pragma unroll
    for (int off = 1; off < 16; off <<= 1) {
        den0 += __shfl_xor(den0, off);
        den1 += __shfl_xor(den1, off);
        den2 += __shfl_xor(den2, off);
        den3 += __shfl_xor(den3, off);
#pragma unroll
        for (int h = 0; h < 4; ++h)
#pragma unroll
            for (int k = 0; k < 6; ++k) a[h][k] += __shfl_xor(a[h][k], off);
    }

    int h = q >> 2;
    float dh = (h == 0) ? den0 : (h == 1) ? den1 : (h == 2) ? den2 : den3;
    float inv = 1.f / (dh + 1e-16f);
    float m[6];
#pragma unroll
    for (int k = 0; k < 6; ++k)
        m[k] = (h == 0) ? a[0][k] : (h == 1) ? a[1][k] : (h == 2) ? a[2][k] : a[3][k];
    int c0 = q * 16;
    unsigned short ob[16];
#pragma unroll
    for (int cc = 0; cc < 16; ++cc) {
        int c = c0 + cc;
        float o = m[0] * W1[c] + m[1] * W1[D1 + c] + m[2] * W1[2 * D1 + c] +
                  m[3] * W1[3 * D1 + c] + m[4] * W1[4 * D1 + c] + m[5] * W1[5 * D1 + c];
        o = o * inv + b1[c];
        o = o > 0.f ? o : (__expf(o) - 1.f);
        ob[cc] = f2b(o);
    }
#pragma unroll
    for (int v = 0; v < 4; ++v)
        ((ushort4*)(outb + (size_t)d * D1 + c0))[v] =
            make_ushort4(ob[v * 4], ob[v * 4 + 1], ob[v * 4 + 2], ob[v * 4 + 3]);
}

// ---------------- bf16 MFMA GEMM: xb = hb @ W2 (+ alpha2 tile) ----------------
__global__ void k_mm(const unsigned short* __restrict__ A, const unsigned short* __restrict__ Bt,
                     unsigned short* __restrict__ C, float* __restrict__ as_,
                     float* __restrict__ ad_, int N) {
    int w = threadIdx.x >> 6;
    int l = threadIdx.x & 63;
    int r0 = blockIdx.x * 64 + w * 16;
    bool half0 = (blockIdx.y == 0);
    int cy = half0 ? 0 : 128;
    int lr = l & 15;
    int lk = (l >> 4) * 8;
    int arow = r0 + lr; if (arow >= N) arow = N - 1;
    const unsigned short* ap = A + (size_t)arow * D1 + lk;
    f32x4 acc[8];
    f32x4 accE = (f32x4){0.f, 0.f, 0.f, 0.f};
#pragma unroll
    for (int i = 0; i < 8; ++i) acc[i] = (f32x4){0.f, 0.f, 0.f, 0.f};
    for (int ks = 0; ks < 8; ++ks) {
        bf16x8 av = *(const bf16x8*)(ap + ks * 32);
#pragma unroll
        for (int ct = 0; ct < 8; ++ct) {
            bf16x8 bv = *(const bf16x8*)(Bt + (size_t)(cy + ct * 16 + lr) * D1 + ks * 32 + lk);
            acc[ct] = __builtin_amdgcn_mfma_f32_16x16x32_bf16(av, bv, acc[ct], 0, 0, 0);
        }
        if (half0) {
            bf16x8 bv = *(const bf16x8*)(Bt + (size_t)(256 + lr) * D1 + ks * 32 + lk);
            accE = __builtin_amdgcn_mfma_f32_16x16x32_bf16(av, bv, accE, 0, 0, 0);
        }
    }
    int rbase = r0 + (l >> 4) * 4;
#pragma unroll
    for (int ct = 0; ct < 8; ++ct) {
#pragma unroll
        for (int r = 0; r < 4; ++r) {
            int row = rbase + r;
            if (row < N) C[(size_t)row * D1 + cy + ct * 16 + lr] = f2b(acc[ct][r]);
        }
    }
    if (half0) {
#pragma unroll
        for (int r = 0; r < 4; ++r) {
            int row = rbase + r;
            if (row < N) {
                float v = accE[r];
                if (lr < 4) as_[row * HEADS + lr] = v;
                else if (lr < 8) ad_[row * HEADS + (lr - 4)] = v;
            }
        }
    }
}

// ---------------- layer-2 aggregate: one wave per dst, no-max softmax ----------------
__global__ void k_aggr2(const int* __restrict__ rowp, const int* __restrict__ csrc,
                        const float* __restrict__ as_, const float* __restrict__ ad_,
                        const unsigned short* __restrict__ xb, const float* __restrict__ bias,
                        unsigned short* __restrict__ outb, int N) {
    int d = blockIdx.x * 4 + (threadIdx.x >> 6);
    if (d >= N) return;
    int t = threadIdx.x & 63;
    int h = t >> 4;
    int lo = rowp[d], hi = rowp[d + 1];
    float adh = ad_[d * HEADS + h];

    float4 acc = {0.f, 0.f, 0.f, 0.f};
    float den = 0.f;
    int k = lo;
    for (; k + 3 < hi; k += 4) {
        int s0 = csrc[k], s1 = csrc[k + 1], s2 = csrc[k + 2], s3 = csrc[k + 3];
        float v0 = as_[s0 * HEADS + h] + adh; v0 = v0 > 0.f ? v0 : NEG * v0;
        float v1 = as_[s1 * HEADS + h] + adh; v1 = v1 > 0.f ? v1 : NEG * v1;
        float v2 = as_[s2 * HEADS + h] + adh; v2 = v2 > 0.f ? v2 : NEG * v2;
        float v3 = as_[s3 * HEADS + h] + adh; v3 = v3 > 0.f ? v3 : NEG * v3;
        float e0 = __expf(v0), e1 = __expf(v1);
        float e2 = __expf(v2), e3 = __expf(v3);
        ushort4 u0 = ((const ushort4*)(xb + (size_t)s0 * D1))[t];
        ushort4 u1 = ((const ushort4*)(xb + (size_t)s1 * D1))[t];
        ushort4 u2 = ((const ushort4*)(xb + (size_t)s2 * D1))[t];
        ushort4 u3 = ((const ushort4*)(xb + (size_t)s3 * D1))[t];
        den += e0 + e1 + e2 + e3;
        acc.x += e0 * b2f(u0.x) + e1 * b2f(u1.x) + e2 * b2f(u2.x) + e3 * b2f(u3.x);
        acc.y += e0 * b2f(u0.y) + e1 * b2f(u1.y) + e2 * b2f(u2.y) + e3 * b2f(u3.y);
        acc.z += e0 * b2f(u0.z) + e1 * b2f(u1.z) + e2 * b2f(u2.z) + e3 * b2f(u3.z);
        acc.w += e0 * b2f(u0.w) + e1 * b2f(u1.w) + e2 * b2f(u2.w) + e3 * b2f(u3.w);
    }
    for (; k < hi; ++k) {
        int s0 = csrc[k];
        float v0 = as_[s0 * HEADS + h] + adh; v0 = v0 > 0.f ? v0 : NEG * v0;
        float e0 = __expf(v0);
        ushort4 u0 = ((const ushort4*)(xb + (size_t)s0 * D1))[t];
        den += e0;
        acc.x += e0 * b2f(u0.x); acc.y += e0 * b2f(u0.y);
        acc.z += e0 * b2f(u0.z); acc.w += e0 * b2f(u0.w);
    }
    float inv = 1.f / (den + 1e-16f);
    float4 bv = ((const float4*)bias)[t];
    float4 o;
    o.x = acc.x * inv + bv.x;
    o.y = acc.y * inv + bv.y;
    o.z = acc.z * inv + bv.z;
    o.w = acc.w * inv + bv.w;
    o.x = o.x > 0.f ? o.x : (__expf(o.x) - 1.f);
    o.y = o.y > 0.f ? o.y : (__expf(o.y) - 1.f);
    o.z = o.z > 0.f ? o.z : (__expf(o.z) - 1.f);
    o.w = o.w > 0.f ? o.w : (__expf(o.w) - 1.f);
    ushort4 ub; ub.x = f2b(o.x); ub.y = f2b(o.y); ub.z = f2b(o.z); ub.w = f2b(o.w);
    ((ushort4*)(outb + (size_t)d * D1))[t] = ub;
}

// ---------------- fused mean-pool + KAN: one block per graph ----------------

__device__ inline float knotf(int j) { return (j - 3) * 0.4f - 1.0f; }

__device__ inline void bspl8(float x, float* out) {
    float t[12];
#pragma unroll
    for (int j = 0; j < 12; ++j) t[j] = knotf(j);
    float bb[11];
#pragma unroll
    for (int j = 0; j < 11; ++j) bb[j] = (x >= t[j] && x < t[j + 1]) ? 1.f : 0.f;
#pragma unroll
    for (int k = 1; k <= 3; ++k) {
#pragma unroll
        for (int j = 0; j + k < 11; ++j) {
            float dl = t[j + k] - t[j];
            float dr = t[j + k + 1] - t[j + 1];
            bb[j] = (x - t[j]) / dl * bb[j] + (t[j + k + 1] - x) / dr * bb[j + 1];
        }
    }
#pragma unroll
    for (int p = 0; p < 8; ++p) out[p] = bb[p];
}

__device__ inline float siluf(float x) { return x / (1.f + __expf(-x)); }

__global__ void k_poolkan(const unsigned short* __restrict__ hb2, const int* __restrict__ batch,
                          const float* __restrict__ bw1, const float* __restrict__ sw1,
                          const float* __restrict__ sc1, const float* __restrict__ bw2,
                          const float* __restrict__ sw2, const float* __restrict__ sc2,
                          float* __restrict__ out, int N) {
    __shared__ float sB[D1][9];
    __shared__ float sS[D1];
    __shared__ float sZ[32];
    int g = blockIdx.x;
    int lo = 0, hi = N;
    while (lo < hi) { int m = (lo + hi) >> 1; if (batch[m] < g) lo = m + 1; else hi = m; }
    int lo2 = lo, hi2 = N;
    while (lo2 < hi2) { int m = (lo2 + hi2) >> 1; if (batch[m] < g + 1) lo2 = m + 1; else hi2 = m; }
    int i = threadIdx.x;
    float s = 0.f;
    for (int n = lo; n < lo2; ++n) s += b2f(hb2[(size_t)n * D1 + i]);
    float xi = s / (float)max(lo2 - lo, 1);
    float b[8];
    bspl8(xi, b);
#pragma unroll
    for (int p = 0; p < 8; ++p) sB[i][p] = b[p];
    sS[i] = siluf(xi);
    __syncthreads();
    int wv = i >> 6, l = i & 63;
    for (int oo = 0; oo < 8; ++oo) {
        int o = wv * 8 + oo;
        float part = 0.f;
        for (int ii = l; ii < D1; ii += 64) {
            float sc = sc1[o * D1 + ii];
            float p0 = sS[ii] * bw1[o * D1 + ii];
            const float* sw = sw1 + ((size_t)o * D1 + ii) * 8;
#pragma unroll
            for (int p = 0; p < 8; ++p) p0 += sB[ii][p] * sw[p] * sc;
            part += p0;
        }
#pragma unroll
        for (int off = 32; off >= 1; off >>= 1) part += __shfl_down(part, off);
        if (l == 0) sZ[o] = part;
    }
    __syncthreads();
    if (i < 64) {
        float part = 0.f;
        if (i < 32) {
            float z = sZ[i];
            float b2a[8];
            bspl8(z, b2a);
            part = siluf(z) * bw2[i];
            float sc = sc2[i];
#pragma unroll
            for (int p = 0; p < 8; ++p) part += b2a[p] * sw2[i * 8 + p] * sc;
        }
#pragma unroll
        for (int off = 32; off >= 1; off >>= 1) part += __shfl_down(part, off);
        if (i == 0) out[g] = part;
    }
}

extern "C" void kernel_launch(void* const* d_in, const int* in_sizes, int n_in,
                              void* d_out, int out_size, void* d_ws, size_t ws_size,
                              hipStream_t stream) {
    const float* x      = (const float*)d_in[0];
    const int*   ei     = (const int*)d_in[1];
    const int*   batch  = (const int*)d_in[2];
    const float* W1     = (const float*)d_in[3];
    const float* asrc1  = (const float*)d_in[4];
    const float* adst1  = (const float*)d_in[5];
    const float* b1     = (const float*)d_in[6];
    const float* W2     = (const float*)d_in[7];
    const float* asrc2  = (const float*)d_in[8];
    const float* adst2  = (const float*)d_in[9];
    const float* b2     = (const float*)d_in[10];
    const float* bw1    = (const float*)d_in[11];
    const float* sw1    = (const float*)d_in[12];
    const float* sc1    = (const float*)d_in[13];
    const float* bw2    = (const float*)d_in[14];
    const float* sw2    = (const float*)d_in[15];
    const float* sc2    = (const float*)d_in[16];
    float* outp = (float*)d_out;

    const int N  = in_sizes[0] / 6;
    const int E  = in_sizes[1] / 2;
    const int ET = E + N;

    char* base = (char*)d_ws;
    unsigned short* hb  = (unsigned short*)base; base += (size_t)N * D1 * 2;  // layer-1 out (bf16)
    unsigned short* xb  = (unsigned short*)base; base += (size_t)N * D1 * 2;  // xw2 (bf16)
    unsigned short* hb2 = (unsigned short*)base; base += (size_t)N * D1 * 2;  // layer-2 out (bf16)
    float* as_ = (float*)base;                   base += (size_t)N * HEADS * 4;
    float* ad_ = (float*)base;                   base += (size_t)N * HEADS * 4;
    unsigned short* Btb = (unsigned short*)base; base += (size_t)272 * D1 * 2;
    float* va1 = (float*)base;                   base += 48 * 4;
    int* deg  = (int*)base;                      base += (size_t)N * 4;
    int* fill = (int*)base;                      base += (size_t)N * 4;
    int* rowp = (int*)base;                      base += (size_t)(N + 1) * 4;
    int* part = (int*)base;                      base += 1024 * 4;
    int* csrc = (int*)base;                      base += (size_t)ET * 4;

    const int TB = 256;
    int gET = cdiv(ET, TB);
    int gSC = cdiv(N + 1, 256);  // scan blocks (must be <= 1024)

    // CSR build + weight prep
    hipMemsetAsync(deg, 0, (size_t)N * sizeof(int), stream);
    hipMemsetAsync(fill, 0, (size_t)N * sizeof(int), stream);
    k_prep<<<1, 64, 0, stream>>>(W1, asrc1, adst1, va1);
    k_deg<<<gET, TB, 0, stream>>>(ei, E, ET, deg);
    k_scan1<<<gSC, 256, 0, stream>>>(deg, rowp, part, N);
    k_scan2<<<1, 1024, 0, stream>>>(part, gSC);
    k_scan3<<<gSC, 256, 0, stream>>>(rowp, part, N + 1);
    k_scatter<<<gET, TB, 0, stream>>>(ei, E, ET, rowp, fill, csrc);
    k_cvtW<<<272, 256, 0, stream>>>(W2, asrc2, adst2, Btb);

    // layer 1 (rank-6 aggregation)
    k_alpha1<<<cdiv(N, TB), TB, 0, stream>>>(x, va1, as_, ad_, N);
    k_aggr1<<<cdiv(N, 16), TB, 0, stream>>>(rowp, csrc, as_, ad_, x, W1, b1, hb, N);

    // layer 2
    k_mm<<<dim3(cdiv(N, 64), 2), TB, 0, stream>>>(hb, Btb, xb, as_, ad_, N);
    k_aggr2<<<cdiv(N, 4), TB, 0, stream>>>(rowp, csrc, as_, ad_, xb, b2, hb2, N);

    // pool + KAN
    k_poolkan<<<NGR, TB, 0, stream>>>(hb2, batch, bw1, sw1, sc1, bw2, sw2, sc2, outp, N);
}